// Round 2
// baseline (139060.400 us; speedup 1.0000x reference)
//
#include <hip/hip_runtime.h>
#include <math.h>

#define HID   256
#define GATES 1024   // 4*HID
#define BATCH 64
#define SEQ   2048

// ---------------------------------------------------------------------------
// GEMM: out[r][g] = sum_k A_row(r)[k] * W[g][k] + bias[g]   (unchanged R1)
// ---------------------------------------------------------------------------
#define BM 128
#define BN 128
#define BK 16
#define LDP 132

__global__ __launch_bounds__(256, 2)
void xg_gemm(const float* __restrict__ A, const float* __restrict__ W,
             const float* __restrict__ bias, float* __restrict__ out,
             int a_bstride, int ch_log2)
{
    __shared__ float As[BK][LDP];
    __shared__ float Ws[BK][LDP];

    const int tid   = threadIdx.x;
    const int m_blk = blockIdx.x * BM;
    const int n_blk = blockIdx.y * BN;

    const int tn = (tid & 15) * 4;
    const int tm = (tid >> 4) * 4;

    float acc[8][8];
    #pragma unroll
    for (int i = 0; i < 8; ++i)
        #pragma unroll
        for (int j = 0; j < 8; ++j) acc[i][j] = 0.f;

    const int lrow = tid >> 2;
    const int lkc  = (tid & 3) * 4;
    const int CHm1 = (1 << ch_log2) - 1;

    for (int k0 = 0; k0 < HID; k0 += BK) {
        #pragma unroll
        for (int p = 0; p < 2; ++p) {
            int row = p * 64 + lrow;
            int r   = m_blk + row;
            int b   = r >> ch_log2;
            int t   = r & CHm1;
            const float4 a = *(const float4*)(A + (size_t)b * a_bstride +
                                              (size_t)t * HID + k0 + lkc);
            As[lkc + 0][row] = a.x;
            As[lkc + 1][row] = a.y;
            As[lkc + 2][row] = a.z;
            As[lkc + 3][row] = a.w;

            int g = n_blk + row;
            const float4 w = *(const float4*)(W + (size_t)g * HID + k0 + lkc);
            Ws[lkc + 0][row] = w.x;
            Ws[lkc + 1][row] = w.y;
            Ws[lkc + 2][row] = w.z;
            Ws[lkc + 3][row] = w.w;
        }
        __syncthreads();

        #pragma unroll
        for (int kk = 0; kk < BK; ++kk) {
            float4 a0 = *(const float4*)&As[kk][tm];
            float4 a1 = *(const float4*)&As[kk][tm + 64];
            float4 b0 = *(const float4*)&Ws[kk][tn];
            float4 b1 = *(const float4*)&Ws[kk][tn + 64];
            float av[8] = {a0.x, a0.y, a0.z, a0.w, a1.x, a1.y, a1.z, a1.w};
            float bv[8] = {b0.x, b0.y, b0.z, b0.w, b1.x, b1.y, b1.z, b1.w};
            #pragma unroll
            for (int i = 0; i < 8; ++i)
                #pragma unroll
                for (int j = 0; j < 8; ++j)
                    acc[i][j] += av[i] * bv[j];
        }
        __syncthreads();
    }

    const float4 bias0 = *(const float4*)&bias[n_blk + tn];
    const float4 bias1 = *(const float4*)&bias[n_blk + tn + 64];
    #pragma unroll
    for (int i = 0; i < 8; ++i) {
        int m  = (i < 4) ? (tm + i) : (tm + 60 + i);
        int gm = m_blk + m;
        float* op = out + (size_t)gm * GATES + n_blk;
        float4 v0 = {acc[i][0] + bias0.x, acc[i][1] + bias0.y,
                     acc[i][2] + bias0.z, acc[i][3] + bias0.w};
        float4 v1 = {acc[i][4] + bias1.x, acc[i][5] + bias1.y,
                     acc[i][6] + bias1.z, acc[i][7] + bias1.w};
        *(float4*)(op + tn)      = v0;
        *(float4*)(op + tn + 64) = v1;
    }
}

// ---------------------------------------------------------------------------
// Recurrence v2: 64 wgs (one per batch) x 512 threads (8 waves).
// Thread tid owns gate rows tid and tid+512.
//   Tier 1 (k=0..KREG-1): weights pinned in VGPRs, loaded once per dispatch.
//   Tier 2 (k=KREG..255): streamed from L2 each step, q-split so that 4
//     consecutive lanes (q=0..3) read one contiguous 64B line -> coalesced.
//     Partial dots land in LDS part[row][q]; row owner sums them.
// __launch_bounds__(512,2): 8-wave wg needs 2 waves/SIMD -> VGPR cap 256.
// ---------------------------------------------------------------------------
#define KREG    80
#define NF4REG  (KREG / 4)          // 20 float4 per owned row in VGPRs
#define NJJ     ((HID - KREG) / 16) // 11: tail float4s per row / 4 q-threads

__device__ __forceinline__ float sigmoid_f(float x) {
    return 1.f / (1.f + __expf(-x));
}
__device__ __forceinline__ float tanh_f(float x) {
    return 1.f - 2.f / (1.f + __expf(2.f * x));
}

__global__ __launch_bounds__(512, 2)
void lstm_rec(const float* __restrict__ xg, const float* __restrict__ w_hh,
              const float* __restrict__ b_hh, float* __restrict__ h_state,
              float* __restrict__ c_state, float* __restrict__ h_out, int CH)
{
    __shared__ float h_s[HID];
    __shared__ float c_s[HID];
    __shared__ float g_s[GATES];
    __shared__ float part[GATES][4];   // 16 KB

    const int b   = blockIdx.x;
    const int tid = threadIdx.x;
    const int r0  = tid;
    const int r1  = tid + 512;
    const int q   = tid & 3;
    const int rr  = tid >> 2;          // 0..127

    if (tid < HID) {
        h_s[tid] = h_state[b * HID + tid];
        c_s[tid] = c_state[b * HID + tid];
    }

    // ---- Tier-1 weights into registers (one-time, 40 float4 loads) ----
    float4 w0[NF4REG], w1[NF4REG];
    {
        const float4* wr0 = (const float4*)(w_hh + (size_t)r0 * HID);
        const float4* wr1 = (const float4*)(w_hh + (size_t)r1 * HID);
        #pragma unroll
        for (int j = 0; j < NF4REG; ++j) { w0[j] = wr0[j]; w1[j] = wr1[j]; }
    }

    const float bh0  = b_hh[r0];
    const float bh1  = b_hh[r1];
    const float* xg_b = xg + (size_t)b * CH * GATES;

    __syncthreads();

    for (int t = 0; t < CH; ++t) {
        // xg for this step (coalesced), issued early
        const float xv0 = xg_b[(size_t)t * GATES + r0];
        const float xv1 = xg_b[(size_t)t * GATES + r1];

        const float4* h4 = (const float4*)h_s;

        // ---- Tier 2: streamed, coalesced q-split ----
        #pragma unroll
        for (int s = 0; s < 4; ++s) {
            const int rA = s * 128 + rr;        // rows 0..511
            const int rB = 512 + rA;            // rows 512..1023
            const float4* rowA = (const float4*)(w_hh + (size_t)rA * HID);
            const float4* rowB = (const float4*)(w_hh + (size_t)rB * HID);
            float4 aA = {0.f, 0.f, 0.f, 0.f};
            float4 aB = {0.f, 0.f, 0.f, 0.f};
            #pragma unroll
            for (int jj = 0; jj < NJJ; ++jj) {
                const int j4 = NF4REG + 4 * jj + q;   // float4 index 20..63
                float4 wa = rowA[j4];
                float4 wb = rowB[j4];
                float4 hh = h4[j4];                   // 4 distinct addrs/wave, conflict-free
                aA.x += wa.x * hh.x;  aA.y += wa.y * hh.y;
                aA.z += wa.z * hh.z;  aA.w += wa.w * hh.w;
                aB.x += wb.x * hh.x;  aB.y += wb.y * hh.y;
                aB.z += wb.z * hh.z;  aB.w += wb.w * hh.w;
            }
            part[rA][q] = (aA.x + aA.y) + (aA.z + aA.w);   // dword = s*512+tid: stride-1
            part[rB][q] = (aB.x + aB.y) + (aB.z + aB.w);
        }

        // ---- Tier 1: register dot (h broadcast, uniform address) ----
        float4 a0 = {0.f, 0.f, 0.f, 0.f};
        float4 a1 = {0.f, 0.f, 0.f, 0.f};
        #pragma unroll
        for (int j = 0; j < NF4REG; ++j) {
            float4 hh = h4[j];
            a0.x += w0[j].x * hh.x;  a0.y += w0[j].y * hh.y;
            a0.z += w0[j].z * hh.z;  a0.w += w0[j].w * hh.w;
            a1.x += w1[j].x * hh.x;  a1.y += w1[j].y * hh.y;
            a1.z += w1[j].z * hh.z;  a1.w += w1[j].w * hh.w;
        }

        __syncthreads();   // partials visible

        // ---- finalize owned gate rows ----
        float4 p0 = *(const float4*)part[r0];
        float4 p1 = *(const float4*)part[r1];
        float g0 = xv0 + bh0 + ((a0.x + a0.y) + (a0.z + a0.w))
                             + ((p0.x + p0.y) + (p0.z + p0.w));
        float g1 = xv1 + bh1 + ((a1.x + a1.y) + (a1.z + a1.w))
                             + ((p1.x + p1.y) + (p1.z + p1.w));
        g_s[r0] = g0;
        g_s[r1] = g1;

        __syncthreads();   // gates visible

        // ---- unit update (gate order i,f,g,o) ----
        if (tid < HID) {
            float ig = sigmoid_f(g_s[tid]);
            float fg = sigmoid_f(g_s[tid + HID]);
            float gg = tanh_f(g_s[tid + 2 * HID]);
            float og = sigmoid_f(g_s[tid + 3 * HID]);
            float c  = fg * c_s[tid] + ig * gg;
            float h  = og * tanh_f(c);
            c_s[tid] = c;
            h_s[tid] = h;
            if (h_out) h_out[((size_t)b * CH + t) * HID + tid] = h;
        }

        __syncthreads();   // h_s/c_s stable for next step
    }

    if (tid < HID) {
        h_state[b * HID + tid] = h_s[tid];
        c_state[b * HID + tid] = c_s[tid];
    }
}

// ---------------------------------------------------------------------------
__global__ void final_linear(const float* __restrict__ h,
                             const float* __restrict__ w_lin,
                             const float* __restrict__ b_lin,
                             float* __restrict__ out)
{
    int b = blockIdx.x;
    int l = threadIdx.x;
    float p = 0.f;
    #pragma unroll
    for (int j = 0; j < 4; ++j) {
        int u = l + j * 64;
        p += h[b * HID + u] * w_lin[u];
    }
    #pragma unroll
    for (int off = 32; off > 0; off >>= 1) p += __shfl_down(p, off, 64);
    if (l == 0) out[b] = p + b_lin[0];
}

// ---------------------------------------------------------------------------
extern "C" void kernel_launch(void* const* d_in, const int* in_sizes, int n_in,
                              void* d_out, int out_size, void* d_ws, size_t ws_size,
                              hipStream_t stream)
{
    const float* input = (const float*)d_in[0];
    const float* w_ih  = (const float*)d_in[1];
    const float* w_hh  = (const float*)d_in[2];
    const float* b_ih  = (const float*)d_in[3];
    const float* b_hh  = (const float*)d_in[4];
    const float* w_lin = (const float*)d_in[5];
    const float* b_lin = (const float*)d_in[6];
    float* out = (float*)d_out;

    const size_t state_bytes = (size_t)4 * BATCH * HID * 4;  // h1,c1,h2,c2
    int CH = 128;
    while (CH > 16) {
        size_t need = state_bytes + (size_t)2 * BATCH * CH * GATES * 4
                                  + (size_t)BATCH * CH * HID * 4;
        if (need <= ws_size) break;
        CH >>= 1;
    }
    const int ch_log2 = __builtin_ctz((unsigned)CH);

    char* ws = (char*)d_ws;
    float* h1 = (float*)ws;
    float* c1 = h1 + BATCH * HID;
    float* h2 = c1 + BATCH * HID;
    float* c2 = h2 + BATCH * HID;
    float* xg1  = (float*)(ws + state_bytes);
    float* xg2  = xg1 + (size_t)BATCH * CH * GATES;
    float* h1ch = xg2 + (size_t)BATCH * CH * GATES;

    hipMemsetAsync(ws, 0, state_bytes, stream);

    const int NC = SEQ / CH;
    dim3 gblk(BATCH * CH / BM, GATES / BN);

    for (int c = 0; c < NC; ++c) {
        xg_gemm<<<gblk, 256, 0, stream>>>(input + (size_t)c * CH * HID, w_ih,
                                          b_ih, xg1, SEQ * HID, ch_log2);
        lstm_rec<<<BATCH, 512, 0, stream>>>(xg1, w_hh, b_hh, h1, c1, h1ch, CH);
        xg_gemm<<<gblk, 256, 0, stream>>>(h1ch, w_ih + GATES * HID,
                                          b_ih + GATES, xg2, CH * HID, ch_log2);
        lstm_rec<<<BATCH, 512, 0, stream>>>(xg2, w_hh + GATES * HID,
                                            b_hh + GATES, h2, c2, nullptr, CH);
    }

    final_linear<<<BATCH, 64, 0, stream>>>(h2, w_lin, b_lin, out);
}

// Round 3
// 25941.495 us; speedup vs baseline: 5.3605x; 5.3605x over previous
//
#include <hip/hip_runtime.h>
#include <math.h>

#define HID   256
#define GATES 1024   // 4*HID
#define BATCH 64
#define SEQ   2048

// ---------------------------------------------------------------------------
// GEMM: out[r][g] = sum_k A_row(r)[k] * W[g][k] + bias[g]   (unchanged R1)
// ---------------------------------------------------------------------------
#define BM 128
#define BN 128
#define BK 16
#define LDP 132

__global__ __launch_bounds__(256, 2)
void xg_gemm(const float* __restrict__ A, const float* __restrict__ W,
             const float* __restrict__ bias, float* __restrict__ out,
             int a_bstride, int ch_log2)
{
    __shared__ float As[BK][LDP];
    __shared__ float Ws[BK][LDP];

    const int tid   = threadIdx.x;
    const int m_blk = blockIdx.x * BM;
    const int n_blk = blockIdx.y * BN;

    const int tn = (tid & 15) * 4;
    const int tm = (tid >> 4) * 4;

    float acc[8][8];
    #pragma unroll
    for (int i = 0; i < 8; ++i)
        #pragma unroll
        for (int j = 0; j < 8; ++j) acc[i][j] = 0.f;

    const int lrow = tid >> 2;
    const int lkc  = (tid & 3) * 4;
    const int CHm1 = (1 << ch_log2) - 1;

    for (int k0 = 0; k0 < HID; k0 += BK) {
        #pragma unroll
        for (int p = 0; p < 2; ++p) {
            int row = p * 64 + lrow;
            int r   = m_blk + row;
            int b   = r >> ch_log2;
            int t   = r & CHm1;
            const float4 a = *(const float4*)(A + (size_t)b * a_bstride +
                                              (size_t)t * HID + k0 + lkc);
            As[lkc + 0][row] = a.x;
            As[lkc + 1][row] = a.y;
            As[lkc + 2][row] = a.z;
            As[lkc + 3][row] = a.w;

            int g = n_blk + row;
            const float4 w = *(const float4*)(W + (size_t)g * HID + k0 + lkc);
            Ws[lkc + 0][row] = w.x;
            Ws[lkc + 1][row] = w.y;
            Ws[lkc + 2][row] = w.z;
            Ws[lkc + 3][row] = w.w;
        }
        __syncthreads();

        #pragma unroll
        for (int kk = 0; kk < BK; ++kk) {
            float4 a0 = *(const float4*)&As[kk][tm];
            float4 a1 = *(const float4*)&As[kk][tm + 64];
            float4 b0 = *(const float4*)&Ws[kk][tn];
            float4 b1 = *(const float4*)&Ws[kk][tn + 64];
            float av[8] = {a0.x, a0.y, a0.z, a0.w, a1.x, a1.y, a1.z, a1.w};
            float bv[8] = {b0.x, b0.y, b0.z, b0.w, b1.x, b1.y, b1.z, b1.w};
            #pragma unroll
            for (int i = 0; i < 8; ++i)
                #pragma unroll
                for (int j = 0; j < 8; ++j)
                    acc[i][j] += av[i] * bv[j];
        }
        __syncthreads();
    }

    const float4 bias0 = *(const float4*)&bias[n_blk + tn];
    const float4 bias1 = *(const float4*)&bias[n_blk + tn + 64];
    #pragma unroll
    for (int i = 0; i < 8; ++i) {
        int m  = (i < 4) ? (tm + i) : (tm + 60 + i);
        int gm = m_blk + m;
        float* op = out + (size_t)gm * GATES + n_blk;
        float4 v0 = {acc[i][0] + bias0.x, acc[i][1] + bias0.y,
                     acc[i][2] + bias0.z, acc[i][3] + bias0.w};
        float4 v1 = {acc[i][4] + bias1.x, acc[i][5] + bias1.y,
                     acc[i][6] + bias1.z, acc[i][7] + bias1.w};
        *(float4*)(op + tn)      = v0;
        *(float4*)(op + tn + 64) = v1;
    }
}

// ---------------------------------------------------------------------------
// Cooperative recurrence: grid = 256 wgs = 4 slices x 64 batch, 512 thr (8 wv).
// blockIdx = s*64 + b  (siblings of a batch land on the same XCD, %8 heuristic).
// wg (b,s) owns 64 units -> 256 rows of w_hh (rows g*256 + s*64 + u, g=0..3),
// pinned in VGPRs (32 float4/thread, loaded ONCE). Per step the only global
// traffic: xg row-read + 64-float h mailbox exchange via agent-scope atomics.
// Double-buffered h mailbox (parity) + monotone per-wg flag counters.
// ---------------------------------------------------------------------------
__device__ __forceinline__ float sigmoid_f(float x) {
    return 1.f / (1.f + __expf(-x));
}
__device__ __forceinline__ float tanh_f(float x) {
    return 1.f - 2.f / (1.f + __expf(2.f * x));
}

__global__ __launch_bounds__(512, 2)
void lstm_rec_coop(const float* __restrict__ xg, const float* __restrict__ w_hh,
                   const float* __restrict__ b_hh, float* __restrict__ hbuf,
                   int* __restrict__ flags, float* __restrict__ c_state,
                   float* __restrict__ h_out, int CH, int flag_base)
{
    __shared__ float hsh[HID];     // h(t-1) staged for the whole wg
    __shared__ float g_s[256];     // per-row matvec partials

    const int s   = blockIdx.x >> 6;        // slice 0..3
    const int b   = blockIdx.x & 63;        // batch
    const int tid = threadIdx.x;
    const int ri  = tid >> 1;               // wg-local row 0..255
    const int hf  = tid & 1;                // column half
    const int grow = (ri >> 6) * 256 + s * 64 + (ri & 63);  // global gate row

    // ---- one-time: weights into VGPRs (32 float4 = 128 VGPRs) ----
    float4 wreg[32];
    {
        const float4* wr = (const float4*)(w_hh + (size_t)grow * HID + hf * 128);
        #pragma unroll
        for (int j = 0; j < 32; ++j) wreg[j] = wr[j];
    }

    // ---- one-time: per-unit state & biases (threads 0..63 are unit owners) --
    const int u = tid;                       // unit (valid for tid<64)
    float c_u = 0.f, bh_i = 0.f, bh_f = 0.f, bh_g = 0.f, bh_o = 0.f;
    if (tid < 64) {
        c_u  = c_state[b * HID + s * 64 + u];
        bh_i = b_hh[          s * 64 + u];
        bh_f = b_hh[HID     + s * 64 + u];
        bh_g = b_hh[2 * HID + s * 64 + u];
        bh_o = b_hh[3 * HID + s * 64 + u];
    }

    const float* xg_b  = xg + (size_t)b * CH * GATES;
    int* const  myflag = flags + b * 4 + s;
    int* const  sflags = flags + b * 4;
    float* const hb0   = hbuf + (size_t)b * HID;            // parity 0
    float* const hb1   = hbuf + (size_t)(64 + b) * HID;     // parity 1

    for (int t = 0; t < CH; ++t) {
        // ---- A: wait for all 4 siblings to have produced h(t-1) ----
        if (tid < 4) {
            const int target = flag_base + t;
            while (__hip_atomic_load(&sflags[tid], __ATOMIC_ACQUIRE,
                                     __HIP_MEMORY_SCOPE_AGENT) < target) {
                __builtin_amdgcn_s_sleep(1);
            }
        }
        __syncthreads();

        // ---- B: h(t-1) -> LDS (coherent reads) ----
        const float* hrd = (t & 1) ? hb1 : hb0;
        if (tid < HID)
            hsh[tid] = __hip_atomic_load(&hrd[tid], __ATOMIC_RELAXED,
                                         __HIP_MEMORY_SCOPE_AGENT);
        __syncthreads();

        // ---- C: matvec partial: row ri, cols [hf*128, hf*128+128) ----
        {
            const float4* h4 = ((const float4*)hsh) + hf * 32;
            float4 a = {0.f, 0.f, 0.f, 0.f};
            #pragma unroll
            for (int j = 0; j < 32; ++j) {
                float4 hh = h4[j];
                a.x += wreg[j].x * hh.x;  a.y += wreg[j].y * hh.y;
                a.z += wreg[j].z * hh.z;  a.w += wreg[j].w * hh.w;
            }
            float p = (a.x + a.y) + (a.z + a.w);
            p += __shfl_xor(p, 1, 64);          // pair-sum both halves
            if (hf == 0) g_s[ri] = p;
        }
        __syncthreads();

        // ---- D: unit update (threads 0..63), mailbox write ----
        if (tid < 64) {
            const size_t xo = (size_t)t * GATES + s * 64 + u;
            float gi = g_s[u]       + xg_b[xo]            + bh_i;
            float gf = g_s[64 + u]  + xg_b[xo + 256]      + bh_f;
            float gg = g_s[128 + u] + xg_b[xo + 512]      + bh_g;
            float go = g_s[192 + u] + xg_b[xo + 768]      + bh_o;
            float ig = sigmoid_f(gi);
            float fg = sigmoid_f(gf);
            float gv = tanh_f(gg);
            float og = sigmoid_f(go);
            c_u = fg * c_u + ig * gv;
            float h = og * tanh_f(c_u);
            float* hwr = (t & 1) ? hb0 : hb1;   // parity (t+1)&1
            __hip_atomic_store(&hwr[s * 64 + u], h, __ATOMIC_RELAXED,
                               __HIP_MEMORY_SCOPE_AGENT);
            if (h_out) h_out[((size_t)b * CH + t) * HID + s * 64 + u] = h;
        }
        __syncthreads();   // drains vmcnt for all waves (incl. mailbox stores)

        if (tid == 0)
            __hip_atomic_fetch_add(myflag, 1, __ATOMIC_RELEASE,
                                   __HIP_MEMORY_SCOPE_AGENT);
    }

    if (tid < 64) c_state[b * HID + s * 64 + u] = c_u;
}

// ---------------------------------------------------------------------------
__global__ void final_linear(const float* __restrict__ h,
                             const float* __restrict__ w_lin,
                             const float* __restrict__ b_lin,
                             float* __restrict__ out)
{
    int b = blockIdx.x;
    int l = threadIdx.x;
    float p = 0.f;
    #pragma unroll
    for (int j = 0; j < 4; ++j) {
        int u = l + j * 64;
        p += h[b * HID + u] * w_lin[u];
    }
    #pragma unroll
    for (int off = 32; off > 0; off >>= 1) p += __shfl_down(p, off, 64);
    if (l == 0) out[b] = p + b_lin[0];
}

// ---------------------------------------------------------------------------
extern "C" void kernel_launch(void* const* d_in, const int* in_sizes, int n_in,
                              void* d_out, int out_size, void* d_ws, size_t ws_size,
                              hipStream_t stream)
{
    const float* input = (const float*)d_in[0];
    const float* w_ih  = (const float*)d_in[1];
    const float* w_hh  = (const float*)d_in[2];
    const float* b_ih  = (const float*)d_in[3];
    const float* b_hh  = (const float*)d_in[4];
    const float* w_lin = (const float*)d_in[5];
    const float* b_lin = (const float*)d_in[6];
    float* out = (float*)d_out;

    // ---- persistent small state (zeroed every launch) ----
    // c1st, c2st: 64*256 each; hbuf1, hbuf2: 2*64*256 each; flags1/2: 256 ints
    const size_t c_elems    = (size_t)BATCH * HID;          // 16384
    const size_t hbuf_elems = (size_t)2 * BATCH * HID;      // 32768
    const size_t zero_elems = 2 * c_elems + 2 * hbuf_elems; // floats
    const size_t zero_bytes = zero_elems * 4 + 2 * 256 * sizeof(int);

    char*  ws    = (char*)d_ws;
    float* c1st  = (float*)ws;
    float* c2st  = c1st + c_elems;
    float* hbuf1 = c2st + c_elems;
    float* hbuf2 = hbuf1 + hbuf_elems;
    int*   flags1 = (int*)(hbuf2 + hbuf_elems);
    int*   flags2 = flags1 + 256;
    float* big   = (float*)(ws + ((zero_bytes + 255) & ~(size_t)255));

    // time-chunk size chosen from ws_size (deterministic across calls)
    int CH = 128;
    while (CH > 16) {
        size_t need = ((zero_bytes + 255) & ~(size_t)255)
                    + ((size_t)2 * BATCH * CH * GATES + (size_t)BATCH * CH * HID) * 4;
        if (need <= ws_size) break;
        CH >>= 1;
    }
    const int ch_log2 = __builtin_ctz((unsigned)CH);

    float* xg1  = big;
    float* xg2  = xg1 + (size_t)BATCH * CH * GATES;
    float* h1ch = xg2 + (size_t)BATCH * CH * GATES;

    hipMemsetAsync(ws, 0, zero_bytes, stream);

    const int NC = SEQ / CH;
    dim3 gblk(BATCH * CH / BM, GATES / BN);

    for (int c = 0; c < NC; ++c) {
        xg_gemm<<<gblk, 256, 0, stream>>>(input + (size_t)c * CH * HID, w_ih,
                                          b_ih, xg1, SEQ * HID, ch_log2);
        lstm_rec_coop<<<256, 512, 0, stream>>>(xg1, w_hh, b_hh, hbuf1, flags1,
                                               c1st, h1ch, CH, c * CH);
        xg_gemm<<<gblk, 256, 0, stream>>>(h1ch, w_ih + GATES * HID,
                                          b_ih + GATES, xg2, CH * HID, ch_log2);
        lstm_rec_coop<<<256, 512, 0, stream>>>(xg2, w_hh + (size_t)GATES * HID,
                                               b_hh + GATES, hbuf2, flags2,
                                               c2st, nullptr, CH, c * CH);
    }

    // final h2 lives in hbuf2 parity (CH&1)==0 buffer (CH is a power of two >=16)
    final_linear<<<BATCH, 64, 0, stream>>>(hbuf2, w_lin, b_lin, out);
}

// Round 4
// 7619.961 us; speedup vs baseline: 18.2495x; 3.4044x over previous
//
#include <hip/hip_runtime.h>
#include <math.h>

#define HID   256
#define GATES 1024   // 4*HID
#define BATCH 64
#define SEQ   2048

// ---------------------------------------------------------------------------
// GEMM: out[r][g] = sum_k A_row(r)[k] * W[g][k] + bias[g]   (unchanged)
// ---------------------------------------------------------------------------
#define BM 128
#define BN 128
#define BK 16
#define LDP 132

__global__ __launch_bounds__(256, 2)
void xg_gemm(const float* __restrict__ A, const float* __restrict__ W,
             const float* __restrict__ bias, float* __restrict__ out,
             int a_bstride, int ch_log2)
{
    __shared__ float As[BK][LDP];
    __shared__ float Ws[BK][LDP];

    const int tid   = threadIdx.x;
    const int m_blk = blockIdx.x * BM;
    const int n_blk = blockIdx.y * BN;

    const int tn = (tid & 15) * 4;
    const int tm = (tid >> 4) * 4;

    float acc[8][8];
    #pragma unroll
    for (int i = 0; i < 8; ++i)
        #pragma unroll
        for (int j = 0; j < 8; ++j) acc[i][j] = 0.f;

    const int lrow = tid >> 2;
    const int lkc  = (tid & 3) * 4;
    const int CHm1 = (1 << ch_log2) - 1;

    for (int k0 = 0; k0 < HID; k0 += BK) {
        #pragma unroll
        for (int p = 0; p < 2; ++p) {
            int row = p * 64 + lrow;
            int r   = m_blk + row;
            int b   = r >> ch_log2;
            int t   = r & CHm1;
            const float4 a = *(const float4*)(A + (size_t)b * a_bstride +
                                              (size_t)t * HID + k0 + lkc);
            As[lkc + 0][row] = a.x;
            As[lkc + 1][row] = a.y;
            As[lkc + 2][row] = a.z;
            As[lkc + 3][row] = a.w;

            int g = n_blk + row;
            const float4 w = *(const float4*)(W + (size_t)g * HID + k0 + lkc);
            Ws[lkc + 0][row] = w.x;
            Ws[lkc + 1][row] = w.y;
            Ws[lkc + 2][row] = w.z;
            Ws[lkc + 3][row] = w.w;
        }
        __syncthreads();

        #pragma unroll
        for (int kk = 0; kk < BK; ++kk) {
            float4 a0 = *(const float4*)&As[kk][tm];
            float4 a1 = *(const float4*)&As[kk][tm + 64];
            float4 b0 = *(const float4*)&Ws[kk][tn];
            float4 b1 = *(const float4*)&Ws[kk][tn + 64];
            float av[8] = {a0.x, a0.y, a0.z, a0.w, a1.x, a1.y, a1.z, a1.w};
            float bv[8] = {b0.x, b0.y, b0.z, b0.w, b1.x, b1.y, b1.z, b1.w};
            #pragma unroll
            for (int i = 0; i < 8; ++i)
                #pragma unroll
                for (int j = 0; j < 8; ++j)
                    acc[i][j] += av[i] * bv[j];
        }
        __syncthreads();
    }

    const float4 bias0 = *(const float4*)&bias[n_blk + tn];
    const float4 bias1 = *(const float4*)&bias[n_blk + tn + 64];
    #pragma unroll
    for (int i = 0; i < 8; ++i) {
        int m  = (i < 4) ? (tm + i) : (tm + 60 + i);
        int gm = m_blk + m;
        float* op = out + (size_t)gm * GATES + n_blk;
        float4 v0 = {acc[i][0] + bias0.x, acc[i][1] + bias0.y,
                     acc[i][2] + bias0.z, acc[i][3] + bias0.w};
        float4 v1 = {acc[i][4] + bias1.x, acc[i][5] + bias1.y,
                     acc[i][6] + bias1.z, acc[i][7] + bias1.w};
        *(float4*)(op + tn)      = v0;
        *(float4*)(op + tn + 64) = v1;
    }
}

// ---------------------------------------------------------------------------
// Cooperative recurrence v3.
// grid = 256 wgs (slice s=0..3, batch b=0..63; blockIdx=s*64+b keeps a batch's
// 4 siblings on one XCD). 512 threads; thread (ri=tid>>1, hf=tid&1) owns the
// hf-half of wg-local row ri -> global gate row (ri>>6)*256 + s*64 + (ri&63).
// Weights: 32 float4/thread pinned in VGPRs; asm memory clobber after the
// load forbids the compiler from sinking the loads back into the t-loop
// (R3 failure mode: VGPR_Count=84 proved re-load from L2 every step).
// Sibling exchange: single-atom mailbox word = (tag<<32 | float bits),
// double-buffered by step parity. No flags, no fences; 2 barriers/step.
// ---------------------------------------------------------------------------
#define MBSTRIDE ((size_t)BATCH * HID)   // ulongs per parity block

__device__ __forceinline__ float sigmoid_f(float x) {
    return 1.f / (1.f + __expf(-x));
}
__device__ __forceinline__ float tanh_f(float x) {
    return 1.f - 2.f / (1.f + __expf(2.f * x));
}

__global__ __launch_bounds__(512, 2)
void lstm_rec_coop(const float* __restrict__ xg, const float* __restrict__ w_hh,
                   const float* __restrict__ b_hh, unsigned long long* mbox,
                   float* __restrict__ c_state, float* __restrict__ h_out,
                   int CH, int gbase)
{
    __shared__ float hsh[HID];     // h(t-1) staged for the whole wg
    __shared__ float g_s[256];     // per-row matvec results

    const int s   = blockIdx.x >> 6;
    const int b   = blockIdx.x & 63;
    const int tid = threadIdx.x;
    const int ri  = tid >> 1;               // wg-local row 0..255
    const int hf  = tid & 1;                // column half
    const int grow = (ri >> 6) * 256 + s * 64 + (ri & 63);

    // ---- one-time: pin 128 weight floats in VGPRs ----
    // read order rotated by hf so the wave's two LDS broadcast addresses in
    // the matvec land in different bank groups (kills the 3.3e7 conflicts).
    float4 wreg[32];
    {
        const float4* wr = (const float4*)(w_hh + (size_t)grow * HID);
        #pragma unroll
        for (int j = 0; j < 32; ++j) {
            const int m = (hf << 5) | ((j + hf) & 31);
            wreg[j] = wr[m];
        }
    }
    // Forbid re-loading wreg from global inside the loop: after this point the
    // compiler must assume memory changed, so the register copies are the only
    // legal source.
    asm volatile("" ::: "memory");

    // ---- one-time: per-unit state & biases (threads 0..63 own units) ----
    float c_u = 0.f, bh_i = 0.f, bh_f = 0.f, bh_g = 0.f, bh_o = 0.f;
    if (tid < 64) {
        c_u  = c_state[b * HID + s * 64 + tid];
        bh_i = b_hh[          s * 64 + tid];
        bh_f = b_hh[HID     + s * 64 + tid];
        bh_g = b_hh[2 * HID + s * 64 + tid];
        bh_o = b_hh[3 * HID + s * 64 + tid];
    }

    const float* xg_b = xg + (size_t)b * CH * GATES;

    for (int t = 0; t < CH; ++t) {
        const int gt = gbase + t;

        // ---- xg prefetch: issue before the spin so latency hides under it --
        float x_i = 0.f, x_f = 0.f, x_g = 0.f, x_o = 0.f;
        if (tid < 64) {
            const size_t xo = (size_t)t * GATES + s * 64 + tid;
            x_i = xg_b[xo];
            x_f = xg_b[xo + 256];
            x_g = xg_b[xo + 512];
            x_o = xg_b[xo + 768];
        }

        // ---- poll own mailbox word (tag==gt) and stage h(t-1) into LDS ----
        if (tid < HID) {
            const unsigned long long* slot =
                mbox + (size_t)(gt & 1) * MBSTRIDE + b * HID + tid;
            unsigned long long w;
            do {
                w = __hip_atomic_load(slot, __ATOMIC_RELAXED,
                                      __HIP_MEMORY_SCOPE_AGENT);
            } while ((unsigned)(w >> 32) != (unsigned)gt);
            hsh[tid] = __uint_as_float((unsigned)w);
        }
        __syncthreads();   // hsh ready; also guarantees D(t-1) done with g_s

        // ---- matvec: row ri, half hf (bank-group-disjoint broadcasts) ----
        {
            const float4* h4 = (const float4*)hsh;
            float4 a = {0.f, 0.f, 0.f, 0.f};
            #pragma unroll
            for (int j = 0; j < 32; ++j) {
                const int m = (hf << 5) | ((j + hf) & 31);
                float4 hh = h4[m];
                a.x += wreg[j].x * hh.x;  a.y += wreg[j].y * hh.y;
                a.z += wreg[j].z * hh.z;  a.w += wreg[j].w * hh.w;
            }
            float p = (a.x + a.y) + (a.z + a.w);
            p += __shfl_xor(p, 1, 64);
            if (hf == 0) g_s[ri] = p;
        }
        __syncthreads();   // g_s ready

        // ---- unit update + publish (gate order i,f,g,o) ----
        if (tid < 64) {
            float gi = g_s[tid]       + x_i + bh_i;
            float gf = g_s[64 + tid]  + x_f + bh_f;
            float gg = g_s[128 + tid] + x_g + bh_g;
            float go = g_s[192 + tid] + x_o + bh_o;
            float ig = sigmoid_f(gi);
            float fg = sigmoid_f(gf);
            float gv = tanh_f(gg);
            float og = sigmoid_f(go);
            c_u = fg * c_u + ig * gv;
            float h = og * tanh_f(c_u);

            unsigned long long wpk =
                ((unsigned long long)(unsigned)(gt + 1) << 32) |
                (unsigned long long)__float_as_uint(h);
            __hip_atomic_store(
                mbox + (size_t)((gt + 1) & 1) * MBSTRIDE + b * HID + s * 64 + tid,
                wpk, __ATOMIC_RELAXED, __HIP_MEMORY_SCOPE_AGENT);

            if (h_out) h_out[((size_t)b * CH + t) * HID + s * 64 + tid] = h;
        }
        // no barrier needed here: next iteration's hsh writes are fenced by
        // the next __syncthreads; g_s(t) readers are the D threads themselves.
    }

    if (tid < 64) c_state[b * HID + s * 64 + tid] = c_u;
}

// ---------------------------------------------------------------------------
// Final linear on the packed parity-0 mailbox (last step 2047 publishes tag
// 2048 into parity 0). Low 32 bits of each word are the h float bits.
// ---------------------------------------------------------------------------
__global__ void final_linear(const unsigned long long* __restrict__ hw,
                             const float* __restrict__ w_lin,
                             const float* __restrict__ b_lin,
                             float* __restrict__ out)
{
    int b = blockIdx.x;
    int l = threadIdx.x;
    float p = 0.f;
    #pragma unroll
    for (int j = 0; j < 4; ++j) {
        int u = l + j * 64;
        p += __uint_as_float((unsigned)hw[b * HID + u]) * w_lin[u];
    }
    #pragma unroll
    for (int off = 32; off > 0; off >>= 1) p += __shfl_down(p, off, 64);
    if (l == 0) out[b] = p + b_lin[0];
}

// ---------------------------------------------------------------------------
extern "C" void kernel_launch(void* const* d_in, const int* in_sizes, int n_in,
                              void* d_out, int out_size, void* d_ws, size_t ws_size,
                              hipStream_t stream)
{
    const float* input = (const float*)d_in[0];
    const float* w_ih  = (const float*)d_in[1];
    const float* w_hh  = (const float*)d_in[2];
    const float* b_ih  = (const float*)d_in[3];
    const float* b_hh  = (const float*)d_in[4];
    const float* w_lin = (const float*)d_in[5];
    const float* b_lin = (const float*)d_in[6];
    float* out = (float*)d_out;

    // ---- persistent state (zeroed every launch; zero word == tag 0, h=0) ----
    const size_t c_elems  = (size_t)BATCH * HID;                 // per layer
    const size_t mb_bytes = 2 * MBSTRIDE * sizeof(unsigned long long);
    char*  ws   = (char*)d_ws;
    float* c1st = (float*)ws;
    float* c2st = c1st + c_elems;
    unsigned long long* mb1 = (unsigned long long*)(c2st + c_elems);
    unsigned long long* mb2 = mb1 + 2 * MBSTRIDE;
    const size_t zero_bytes = 2 * c_elems * 4 + 2 * mb_bytes;
    float* big  = (float*)(ws + ((zero_bytes + 255) & ~(size_t)255));

    int CH = 128;
    while (CH > 16) {
        size_t need = ((zero_bytes + 255) & ~(size_t)255)
                    + ((size_t)2 * BATCH * CH * GATES + (size_t)BATCH * CH * HID) * 4;
        if (need <= ws_size) break;
        CH >>= 1;
    }
    const int ch_log2 = __builtin_ctz((unsigned)CH);

    float* xg1  = big;
    float* xg2  = xg1 + (size_t)BATCH * CH * GATES;
    float* h1ch = xg2 + (size_t)BATCH * CH * GATES;

    hipMemsetAsync(ws, 0, zero_bytes, stream);

    const int NC = SEQ / CH;
    dim3 gblk(BATCH * CH / BM, GATES / BN);

    for (int c = 0; c < NC; ++c) {
        xg_gemm<<<gblk, 256, 0, stream>>>(input + (size_t)c * CH * HID, w_ih,
                                          b_ih, xg1, SEQ * HID, ch_log2);
        lstm_rec_coop<<<256, 512, 0, stream>>>(xg1, w_hh, b_hh, mb1,
                                               c1st, h1ch, CH, c * CH);
        xg_gemm<<<gblk, 256, 0, stream>>>(h1ch, w_ih + GATES * HID,
                                          b_ih + GATES, xg2, CH * HID, ch_log2);
        lstm_rec_coop<<<256, 512, 0, stream>>>(xg2, w_hh + (size_t)GATES * HID,
                                               b_hh + GATES, mb2,
                                               c2st, nullptr, CH, c * CH);
    }

    // last h2 (step 2047, tag 2048) sits in mb2 parity-0 block
    final_linear<<<BATCH, 64, 0, stream>>>(mb2, w_lin, b_lin, out);
}